// Round 1
// baseline (390.952 us; speedup 1.0000x reference)
//
#include <hip/hip_runtime.h>
#include <hip/hip_bf16.h>

// ---------------------------------------------------------------------------
// MHSA + MLP block, B=4 C=128 H=W=64 (N=4096), HEADS=4 HD=32, HIDDEN=256.
// Pipeline: LN1 -> QKV gemm -> flash-attn (bf16 MFMA) -> proj+res -> LN2
//           -> fc1+GELU -> fc2+res.
// ws layout (floats): R0[0,2M) xln1/attnout/xln2 (reused 3x), Q[2M,4M),
//                     K[4M,6M), V[6M,8M); HB=[2M,6M) after attn; X1=[6M,8M).
// ---------------------------------------------------------------------------

typedef __attribute__((ext_vector_type(4))) float f32x4;
typedef __attribute__((ext_vector_type(8))) short bf16x8;       // MFMA A/B frag
typedef __attribute__((ext_vector_type(8))) unsigned short ushort8;

#define C_ 128
#define N_ 4096

__device__ inline unsigned short f2bf(float f) {   // fp32 -> bf16 RNE
  unsigned int x = __float_as_uint(f);
  x += 0x7fffu + ((x >> 16) & 1u);
  return (unsigned short)(x >> 16);
}

__device__ inline ushort8 cvt8(f32x4 a, f32x4 b) {
  ushort8 u;
  u[0] = f2bf(a[0]); u[1] = f2bf(a[1]); u[2] = f2bf(a[2]); u[3] = f2bf(a[3]);
  u[4] = f2bf(b[0]); u[5] = f2bf(b[1]); u[6] = f2bf(b[2]); u[7] = f2bf(b[3]);
  return u;
}

// ---------------------------------------------------------------------------
// LayerNorm over channels. Input [B,C,N] (NCHW), output rows [B*N, C].
// LDS transpose tile so both global read (over n) and write (over c) coalesce.
// ---------------------------------------------------------------------------
__global__ __launch_bounds__(256) void ln_kernel(const float* __restrict__ xin,
                                                 const float* __restrict__ gamma,
                                                 const float* __restrict__ beta,
                                                 float* __restrict__ outp) {
  __shared__ float tile[128][65];
  __shared__ float ps[4][64];
  __shared__ float pss[4][64];
  __shared__ float mu_s[64];
  __shared__ float rs_s[64];
  const int t = threadIdx.x;
  const int b = blockIdx.x >> 6;          // 64 tiles of 64 positions per batch
  const int n0 = (blockIdx.x & 63) << 6;
  const float* xb = xin + (size_t)b * C_ * N_ + n0;
#pragma unroll
  for (int i = 0; i < 32; ++i) {
    int lin = i * 256 + t;
    int c = lin >> 6, p = lin & 63;
    tile[c][p] = xb[(size_t)c * N_ + p];
  }
  __syncthreads();
  {
    int p = t & 63, part = t >> 6;
    float s = 0.f, ss = 0.f;
#pragma unroll
    for (int j = 0; j < 32; ++j) {
      float v = tile[part * 32 + j][p];
      s += v; ss += v * v;
    }
    ps[part][p] = s; pss[part][p] = ss;
  }
  __syncthreads();
  if (t < 64) {
    int p = t;
    float su = ps[0][p] + ps[1][p] + ps[2][p] + ps[3][p];
    float sq = pss[0][p] + pss[1][p] + pss[2][p] + pss[3][p];
    float mu = su * (1.f / 128.f);
    float var = sq * (1.f / 128.f) - mu * mu;
    mu_s[p] = mu;
    rs_s[p] = rsqrtf(var + 1e-5f);
  }
  __syncthreads();
  float* ob = outp + (size_t)(b * N_ + n0) * C_;
#pragma unroll
  for (int i = 0; i < 32; ++i) {
    int lin = i * 256 + t;
    int p = lin >> 7, c = lin & 127;
    ob[(size_t)p * C_ + c] = (tile[c][p] - mu_s[p]) * rs_s[p] * gamma[c] + beta[c];
  }
}

// ---------------------------------------------------------------------------
// fp32 tiled GEMM core: acc[4][4] += A[row0+r][:] dot W[col0+c][:].
// A: [M,K] row-major; W: [O,K] row-major. K staged transposed in LDS so the
// inner loop is two b128 reads (~2-way conflicts) per 16 FMA.
// ---------------------------------------------------------------------------
template <int KDIM>
__device__ inline void gemm_core(const float* __restrict__ A, const float* __restrict__ W,
                                 int row0, int col0, int t, float acc[4][4]) {
  __shared__ __align__(16) float As[64][68];   // [k][row]
  __shared__ __align__(16) float Ws[64][68];   // [k][col]
  const int r0 = (t >> 4) << 2;
  const int c0 = (t & 15) << 2;
  for (int kc = 0; kc < KDIM; kc += 64) {
    __syncthreads();
#pragma unroll
    for (int i = 0; i < 4; ++i) {
      int lin = i * 256 + t;
      int rr = lin >> 4, kk = (lin & 15) << 2;
      f32x4 av = *(const f32x4*)&A[(size_t)(row0 + rr) * KDIM + kc + kk];
      As[kk][rr] = av[0]; As[kk + 1][rr] = av[1]; As[kk + 2][rr] = av[2]; As[kk + 3][rr] = av[3];
      f32x4 wv = *(const f32x4*)&W[(size_t)(col0 + rr) * KDIM + kc + kk];
      Ws[kk][rr] = wv[0]; Ws[kk + 1][rr] = wv[1]; Ws[kk + 2][rr] = wv[2]; Ws[kk + 3][rr] = wv[3];
    }
    __syncthreads();
#pragma unroll
    for (int k = 0; k < 64; ++k) {
      f32x4 a = *(const f32x4*)&As[k][r0];
      f32x4 wv = *(const f32x4*)&Ws[k][c0];
#pragma unroll
      for (int i = 0; i < 4; ++i)
#pragma unroll
        for (int j = 0; j < 4; ++j)
          acc[i][j] = fmaf(a[i], wv[j], acc[i][j]);
    }
  }
}

// QKV: rows = xln [16384,128], W = qkv_w [384,128].
// Scatter: Q,K -> [bh][n][32]; V -> [bh][32][n] (pre-transposed for PV frag).
__global__ __launch_bounds__(256) void qkv_kernel(const float* __restrict__ XLN,
                                                  const float* __restrict__ Wq,
                                                  float* __restrict__ Qb,
                                                  float* __restrict__ Kb,
                                                  float* __restrict__ Vb) {
  const int t = threadIdx.x;
  const int row0 = (blockIdx.x & 255) << 6;
  const int col0 = (blockIdx.x >> 8) << 6;
  float acc[4][4] = {};
  gemm_core<128>(XLN, Wq, row0, col0, t, acc);
  const int r0 = (t >> 4) << 2, c0 = (t & 15) << 2;
#pragma unroll
  for (int i = 0; i < 4; ++i) {
    int gp = row0 + r0 + i;
    int b = gp >> 12, n = gp & 4095;
#pragma unroll
    for (int j = 0; j < 4; ++j) {
      int o = col0 + c0 + j;
      int ch = o & 127;
      int hh = ch >> 5, d = ch & 31;
      float v = acc[i][j];
      if (o < 256) {
        float* P = (o < 128) ? Qb : Kb;
        P[((size_t)(b * 4 + hh) * 4096 + n) * 32 + d] = v;
      } else {
        Vb[((size_t)(b * 4 + hh) * 32 + d) * 4096 + n] = v;
      }
    }
  }
}

// ---------------------------------------------------------------------------
// Flash attention, bf16 MFMA 16x16x32. One block = one (b,h) x 64-query tile;
// 4 waves x 16 q-rows. C/D layout: col=lane&15 (key/d), row=(lane>>4)*4+reg (q).
// A/B frags: row/col = lane&15, k = (lane>>4)*8 + i (8 consecutive, b128).
// blockIdx swizzle keeps both q-halves of a (b,h) on one XCD (K/V L2-resident).
// ---------------------------------------------------------------------------
__global__ __launch_bounds__(256) void attn_kernel(const float* __restrict__ Qg,
                                                   const float* __restrict__ Kg,
                                                   const float* __restrict__ Vg,
                                                   float* __restrict__ AO) {
  __shared__ __align__(16) unsigned short Qa[64][40];
  __shared__ __align__(16) unsigned short Ks[64][40];
  __shared__ __align__(16) unsigned short Vt[32][72];
  __shared__ __align__(16) unsigned short Ps[64][72];
  const int id = blockIdx.x;                     // grid 1024
  const int bh = (id & 7) | ((id >> 9) << 3);    // xcd = bh % 8
  const int qt = (id >> 3) & 63;
  const int b = bh >> 2, h = bh & 3;
  const float* Qp = Qg + ((size_t)bh * 4096 + qt * 64) * 32;
  const float* Kp = Kg + (size_t)bh * 4096 * 32;
  const float* Vp = Vg + (size_t)bh * 32 * 4096;
  const int t = threadIdx.x;
  const int lane = t & 63, w = t >> 6;
  const int l15 = lane & 15, g = lane >> 4;

  {  // stage Q tile -> bf16 LDS
    int row = t >> 2, d0 = (t & 3) << 3;
    const float* src = Qp + row * 32 + d0;
    *(ushort8*)&Qa[row][d0] = cvt8(*(const f32x4*)src, *(const f32x4*)(src + 4));
  }
  __syncthreads();
  const bf16x8 aQ = *(const bf16x8*)&Qa[(w << 4) + l15][g << 3];  // hoisted A-frag

  const f32x4 zero = {0.f, 0.f, 0.f, 0.f};
  f32x4 opv[2]; opv[0] = zero; opv[1] = zero;
  float m_r[4] = {-1e30f, -1e30f, -1e30f, -1e30f};
  float l_r[4] = {0.f, 0.f, 0.f, 0.f};
  const float scale = 0.17677669529663687f;      // 1/sqrt(32)

  for (int kt = 0; kt < 64; ++kt) {
    {  // stage K chunk [64][32] and V chunk [32][64]
      int row = t >> 2, d0 = (t & 3) << 3;
      const float* src = Kp + (size_t)(kt * 64 + row) * 32 + d0;
      *(ushort8*)&Ks[row][d0] = cvt8(*(const f32x4*)src, *(const f32x4*)(src + 4));
      int d = t >> 3, c0 = (t & 7) << 3;
      const float* vsrc = Vp + (size_t)d * 4096 + kt * 64 + c0;
      *(ushort8*)&Vt[d][c0] = cvt8(*(const f32x4*)vsrc, *(const f32x4*)(vsrc + 4));
    }
    __syncthreads();

    f32x4 s[4];
#pragma unroll
    for (int ks = 0; ks < 4; ++ks) {   // S[16q][16key] x4, k-dim = HD = 32
      bf16x8 bK = *(const bf16x8*)&Ks[(ks << 4) + l15][g << 3];
      s[ks] = __builtin_amdgcn_mfma_f32_16x16x32_bf16(aQ, bK, zero, 0, 0, 0);
    }
#pragma unroll
    for (int r = 0; r < 4; ++r) {      // online softmax per owned q-row
      float v0 = s[0][r] * scale, v1 = s[1][r] * scale;
      float v2 = s[2][r] * scale, v3 = s[3][r] * scale;
      float m0 = fmaxf(fmaxf(v0, v1), fmaxf(v2, v3));
      m0 = fmaxf(m0, __shfl_xor(m0, 1, 16));
      m0 = fmaxf(m0, __shfl_xor(m0, 2, 16));
      m0 = fmaxf(m0, __shfl_xor(m0, 4, 16));
      m0 = fmaxf(m0, __shfl_xor(m0, 8, 16));
      float mn = fmaxf(m_r[r], m0);
      float al = __expf(m_r[r] - mn);
      m_r[r] = mn;
      float p0 = __expf(v0 - mn), p1 = __expf(v1 - mn);
      float p2 = __expf(v2 - mn), p3 = __expf(v3 - mn);
      float rs = p0 + p1 + p2 + p3;
      rs += __shfl_xor(rs, 1, 16);
      rs += __shfl_xor(rs, 2, 16);
      rs += __shfl_xor(rs, 4, 16);
      rs += __shfl_xor(rs, 8, 16);
      l_r[r] = l_r[r] * al + rs;
      opv[0][r] *= al;
      opv[1][r] *= al;
      int qrow = (w << 4) + (g << 2) + r;
      Ps[qrow][l15]      = f2bf(p0);
      Ps[qrow][16 + l15] = f2bf(p1);
      Ps[qrow][32 + l15] = f2bf(p2);
      Ps[qrow][48 + l15] = f2bf(p3);
    }
    __syncthreads();   // P visible (wave-private stripe, but play safe)
#pragma unroll
    for (int kb = 0; kb < 2; ++kb) {   // PV: O[16q][32d] += P[16][32k] V[32k][16d]
      bf16x8 aP = *(const bf16x8*)&Ps[(w << 4) + l15][(kb << 5) + (g << 3)];
#pragma unroll
      for (int dt = 0; dt < 2; ++dt) {
        bf16x8 bV = *(const bf16x8*)&Vt[(dt << 4) + l15][(kb << 5) + (g << 3)];
        opv[dt] = __builtin_amdgcn_mfma_f32_16x16x32_bf16(aP, bV, opv[dt], 0, 0, 0);
      }
    }
    __syncthreads();   // before restaging K/V
  }

  float* aob = AO + (size_t)(b * 4096 + qt * 64) * 128;
#pragma unroll
  for (int r = 0; r < 4; ++r) {
    float inv = 1.f / l_r[r];
    int qrow = (w << 4) + (g << 2) + r;
#pragma unroll
    for (int dt = 0; dt < 2; ++dt) {
      int ch = (h << 5) + (dt << 4) + l15;
      aob[(size_t)qrow * 128 + ch] = opv[dt][r] * inv;
    }
  }
}

// proj + residual: X1[b,c,n] = x[b,c,n] + AO.proj_w + proj_b
__global__ __launch_bounds__(256) void proj_kernel(const float* __restrict__ AO,
                                                   const float* __restrict__ Wp,
                                                   const float* __restrict__ bp,
                                                   const float* __restrict__ x,
                                                   float* __restrict__ X1) {
  const int t = threadIdx.x;
  const int row0 = (blockIdx.x & 255) << 6;
  const int col0 = (blockIdx.x >> 8) << 6;
  float acc[4][4] = {};
  gemm_core<128>(AO, Wp, row0, col0, t, acc);
  const int r0 = (t >> 4) << 2, c0 = (t & 15) << 2;
#pragma unroll
  for (int i = 0; i < 4; ++i) {
    int gp = row0 + r0 + i;
    int b = gp >> 12, n = gp & 4095;
#pragma unroll
    for (int j = 0; j < 4; ++j) {
      int c = col0 + c0 + j;
      size_t idx = ((size_t)(b * C_ + c) << 12) + n;
      X1[idx] = x[idx] + acc[i][j] + bp[c];
    }
  }
}

// fc1 + exact GELU -> H [16384, 256]
__global__ __launch_bounds__(256) void fc1_kernel(const float* __restrict__ XLN2,
                                                  const float* __restrict__ W1,
                                                  const float* __restrict__ b1,
                                                  float* __restrict__ Hb) {
  const int t = threadIdx.x;
  const int row0 = (blockIdx.x & 255) << 6;
  const int col0 = (blockIdx.x >> 8) << 6;
  float acc[4][4] = {};
  gemm_core<128>(XLN2, W1, row0, col0, t, acc);
  const int r0 = (t >> 4) << 2, c0 = (t & 15) << 2;
#pragma unroll
  for (int i = 0; i < 4; ++i) {
    int gp = row0 + r0 + i;
#pragma unroll
    for (int j = 0; j < 4; ++j) {
      int o = col0 + c0 + j;
      float v = acc[i][j] + b1[o];
      v = 0.5f * v * (1.f + erff(v * 0.70710678118654752f));
      Hb[(size_t)gp * 256 + o] = v;
    }
  }
}

// fc2 + residual -> out NCHW
__global__ __launch_bounds__(256) void fc2_kernel(const float* __restrict__ Hb,
                                                  const float* __restrict__ W2,
                                                  const float* __restrict__ b2,
                                                  const float* __restrict__ X1,
                                                  float* __restrict__ outp) {
  const int t = threadIdx.x;
  const int row0 = (blockIdx.x & 255) << 6;
  const int col0 = (blockIdx.x >> 8) << 6;
  float acc[4][4] = {};
  gemm_core<256>(Hb, W2, row0, col0, t, acc);
  const int r0 = (t >> 4) << 2, c0 = (t & 15) << 2;
#pragma unroll
  for (int i = 0; i < 4; ++i) {
    int gp = row0 + r0 + i;
    int b = gp >> 12, n = gp & 4095;
#pragma unroll
    for (int j = 0; j < 4; ++j) {
      int c = col0 + c0 + j;
      size_t idx = ((size_t)(b * C_ + c) << 12) + n;
      outp[idx] = X1[idx] + acc[i][j] + b2[c];
    }
  }
}

extern "C" void kernel_launch(void* const* d_in, const int* in_sizes, int n_in,
                              void* d_out, int out_size, void* d_ws, size_t ws_size,
                              hipStream_t stream) {
  (void)in_sizes; (void)n_in; (void)out_size; (void)ws_size;
  const float* x     = (const float*)d_in[0];
  const float* ln1w  = (const float*)d_in[1];
  const float* ln1b  = (const float*)d_in[2];
  const float* qkvw  = (const float*)d_in[3];
  const float* projw = (const float*)d_in[4];
  const float* projb = (const float*)d_in[5];
  const float* ln2w  = (const float*)d_in[6];
  const float* ln2b  = (const float*)d_in[7];
  const float* fc1w  = (const float*)d_in[8];
  const float* fc1b  = (const float*)d_in[9];
  const float* fc2w  = (const float*)d_in[10];
  const float* fc2b  = (const float*)d_in[11];
  float* out = (float*)d_out;
  float* ws  = (float*)d_ws;

  float* R0 = ws;                        // 2M floats, reused xln1/AO/xln2
  float* Qb = ws + (2u << 20);
  float* Kb = ws + (4u << 20);
  float* Vb = ws + (6u << 20);
  float* HB = ws + (2u << 20);           // after attn, overlaps Q+K
  float* X1 = ws + (6u << 20);           // after attn, overlaps V

  ln_kernel<<<dim3(256), dim3(256), 0, stream>>>(x, ln1w, ln1b, R0);
  qkv_kernel<<<dim3(1536), dim3(256), 0, stream>>>(R0, qkvw, Qb, Kb, Vb);
  attn_kernel<<<dim3(1024), dim3(256), 0, stream>>>(Qb, Kb, Vb, R0);
  proj_kernel<<<dim3(512), dim3(256), 0, stream>>>(R0, projw, projb, x, X1);
  ln_kernel<<<dim3(256), dim3(256), 0, stream>>>(X1, ln2w, ln2b, R0);
  fc1_kernel<<<dim3(1024), dim3(256), 0, stream>>>(R0, fc1w, fc1b, HB);
  fc2_kernel<<<dim3(512), dim3(256), 0, stream>>>(HB, fc2w, fc2b, X1, out);
}